// Round 1
// baseline (691.433 us; speedup 1.0000x reference)
//
#include <hip/hip_runtime.h>

#define R_DIM 1024
#define N_DIM 1024
#define FEAT  1024
#define EMB   64
#define GROUP 16
#define DG    64

struct __align__(8) h4 { _Float16 x, y, z, w; };

// ---------------------------------------------------------------------------
// K1: q = roi @ Wq^T + bq ; k = roi @ Wk^T + bk   (fused, shared A-tile)
// 64x64 tile, BK=16, 256 threads, 4x4 outputs per thread for each of q,k.
// Register prefetch hides global latency (grid = 256 blocks = 1 block/CU).
// ---------------------------------------------------------------------------
__global__ __launch_bounds__(256) void qk_gemm(
    const float* __restrict__ roi, const float* __restrict__ Wq,
    const float* __restrict__ bq,  const float* __restrict__ Wk,
    const float* __restrict__ bk,  float* __restrict__ qout,
    float* __restrict__ kout)
{
  __shared__ float aT[16][68];
  __shared__ float bqT[16][68];
  __shared__ float bkT[16][68];
  const int t  = threadIdx.x;
  const int r0 = blockIdx.x * 64, c0 = blockIdx.y * 64;
  const int lr = t >> 2, lk = (t & 3) << 2;
  const int ty = t >> 4, tx = t & 15;
  const float* ap  = roi + (r0 + lr) * FEAT + lk;
  const float* bqp = Wq  + (c0 + lr) * FEAT + lk;
  const float* bkp = Wk  + (c0 + lr) * FEAT + lk;
  float4 av  = *(const float4*)ap;
  float4 bqv = *(const float4*)bqp;
  float4 bkv = *(const float4*)bkp;
  float accq[4][4] = {}, acck[4][4] = {};
  for (int k0 = 0; k0 < FEAT; k0 += 16) {
    aT[lk+0][lr]=av.x;   aT[lk+1][lr]=av.y;   aT[lk+2][lr]=av.z;   aT[lk+3][lr]=av.w;
    bqT[lk+0][lr]=bqv.x; bqT[lk+1][lr]=bqv.y; bqT[lk+2][lr]=bqv.z; bqT[lk+3][lr]=bqv.w;
    bkT[lk+0][lr]=bkv.x; bkT[lk+1][lr]=bkv.y; bkT[lk+2][lr]=bkv.z; bkT[lk+3][lr]=bkv.w;
    __syncthreads();
    const bool more = (k0 + 16) < FEAT;
    float4 av_n, bqv_n, bkv_n;
    if (more) {
      av_n  = *(const float4*)(ap  + k0 + 16);
      bqv_n = *(const float4*)(bqp + k0 + 16);
      bkv_n = *(const float4*)(bkp + k0 + 16);
    }
#pragma unroll
    for (int kk = 0; kk < 16; ++kk) {
      const float4 a4 = *(const float4*)&aT[kk][ty << 2];
      const float4 q4 = *(const float4*)&bqT[kk][tx << 2];
      const float4 k4 = *(const float4*)&bkT[kk][tx << 2];
      const float ar[4] = {a4.x, a4.y, a4.z, a4.w};
      const float qr[4] = {q4.x, q4.y, q4.z, q4.w};
      const float kr[4] = {k4.x, k4.y, k4.z, k4.w};
#pragma unroll
      for (int i = 0; i < 4; ++i)
#pragma unroll
        for (int j = 0; j < 4; ++j) {
          accq[i][j] += ar[i] * qr[j];
          acck[i][j] += ar[i] * kr[j];
        }
    }
    __syncthreads();
    if (more) { av = av_n; bqv = bqv_n; bkv = bkv_n; }
  }
  const float4 bq4 = *(const float4*)(bq + c0 + (tx << 2));
  const float4 bk4 = *(const float4*)(bk + c0 + (tx << 2));
  const float bqr[4] = {bq4.x, bq4.y, bq4.z, bq4.w};
  const float bkr[4] = {bk4.x, bk4.y, bk4.z, bk4.w};
#pragma unroll
  for (int i = 0; i < 4; ++i) {
    float4 oq, ok;
    float* oqf = (float*)&oq; float* okf = (float*)&ok;
#pragma unroll
    for (int j = 0; j < 4; ++j) { oqf[j] = accq[i][j] + bqr[j]; okf[j] = acck[i][j] + bkr[j]; }
    const int row = r0 + (ty << 2) + i;
    *(float4*)(qout + row * FEAT + c0 + (tx << 2)) = oq;
    *(float4*)(kout + row * FEAT + c0 + (tx << 2)) = ok;
  }
}

// ---------------------------------------------------------------------------
// K2: logw[r,g,n] = log(max(relu(pos_emb[r,n,:].Wp[g,:] + bp[g]), 1e-6)), f16
// Each thread handles 2 n-rows (halves LDS Wp re-reads); memory-bound (256 MB).
// ---------------------------------------------------------------------------
__global__ __launch_bounds__(256) void pos_log(
    const float* __restrict__ pe, const float* __restrict__ Wp,
    const float* __restrict__ bp, _Float16* __restrict__ logw)
{
  __shared__ float wp[16][64];
  __shared__ float bps[16];
  const int t = threadIdx.x;
  ((float4*)&wp[0][0])[t] = ((const float4*)Wp)[t];   // 16*64 floats = 256 float4
  if (t < 16) bps[t] = bp[t];
  __syncthreads();
  const int bid = blockIdx.x;            // 2048 blocks
  const int r   = bid >> 1;
  const int na  = ((bid & 1) << 9) + t;  // n and n+256
  const int nb  = na + 256;
  const float* p0 = pe + (r * (size_t)N_DIM + na) * EMB;
  const float* p1 = pe + (r * (size_t)N_DIM + nb) * EMB;
  float acc0[16] = {}, acc1[16] = {};
#pragma unroll
  for (int e4 = 0; e4 < 16; ++e4) {
    const float4 x0 = *(const float4*)(p0 + (e4 << 2));
    const float4 x1 = *(const float4*)(p1 + (e4 << 2));
#pragma unroll
    for (int g = 0; g < 16; ++g) {
      const float4 w = *(const float4*)&wp[g][e4 << 2];
      acc0[g] += x0.x*w.x + x0.y*w.y + x0.z*w.z + x0.w*w.w;
      acc1[g] += x1.x*w.x + x1.y*w.y + x1.z*w.z + x1.w*w.w;
    }
  }
#pragma unroll
  for (int g = 0; g < 16; ++g) {
    const float v0 = fmaxf(acc0[g] + bps[g], 1e-6f);  // relu then clip == max(x,1e-6)
    const float v1 = fmaxf(acc1[g] + bps[g], 1e-6f);
    logw[(((r << 4) + g) << 10) + na] = (_Float16)__logf(v0);
    logw[(((r << 4) + g) << 10) + nb] = (_Float16)__logf(v1);
  }
}

// ---------------------------------------------------------------------------
// K3: KC[g][n][o] = sum_f roi[n][f] * Wc[g][o][f]   (no bias)
// Same tile structure as qk_gemm, single B.
// ---------------------------------------------------------------------------
__global__ __launch_bounds__(256) void kc_gemm(
    const float* __restrict__ roi, const float* __restrict__ Wc,
    float* __restrict__ kc)
{
  __shared__ float aT[16][68];
  __shared__ float bT[16][68];
  const int t  = threadIdx.x;
  const int n0 = blockIdx.x * 64;
  const int g  = blockIdx.y;
  const int lr = t >> 2, lk = (t & 3) << 2;
  const int ty = t >> 4, tx = t & 15;
  const float* ap  = roi + (n0 + lr) * FEAT + lk;
  const float* bp_ = Wc  + (g * DG + lr) * FEAT + lk;
  float4 av = *(const float4*)ap;
  float4 bv = *(const float4*)bp_;
  float acc[4][4] = {};
  for (int k0 = 0; k0 < FEAT; k0 += 16) {
    aT[lk+0][lr]=av.x; aT[lk+1][lr]=av.y; aT[lk+2][lr]=av.z; aT[lk+3][lr]=av.w;
    bT[lk+0][lr]=bv.x; bT[lk+1][lr]=bv.y; bT[lk+2][lr]=bv.z; bT[lk+3][lr]=bv.w;
    __syncthreads();
    const bool more = (k0 + 16) < FEAT;
    float4 av_n, bv_n;
    if (more) {
      av_n = *(const float4*)(ap  + k0 + 16);
      bv_n = *(const float4*)(bp_ + k0 + 16);
    }
#pragma unroll
    for (int kk = 0; kk < 16; ++kk) {
      const float4 a4 = *(const float4*)&aT[kk][ty << 2];
      const float4 b4 = *(const float4*)&bT[kk][tx << 2];
      const float ar[4] = {a4.x, a4.y, a4.z, a4.w};
      const float br[4] = {b4.x, b4.y, b4.z, b4.w};
#pragma unroll
      for (int i = 0; i < 4; ++i)
#pragma unroll
        for (int j = 0; j < 4; ++j) acc[i][j] += ar[i] * br[j];
    }
    __syncthreads();
    if (more) { av = av_n; bv = bv_n; }
  }
#pragma unroll
  for (int i = 0; i < 4; ++i) {
    float4 o; float* of = (float*)&o;
#pragma unroll
    for (int j = 0; j < 4; ++j) of[j] = acc[i][j];
    *(float4*)(kc + (size_t)((g << 10) + n0 + (ty << 2) + i) * DG + (tx << 2)) = o;
  }
}

// ---------------------------------------------------------------------------
// K4: fused attention. Block = (16 r-rows, one g). s = q.k^T*scale + logw,
// two-pass softmax (shuffle reduce), exp'd weights -> LDS f16, then att @ KC.
// ---------------------------------------------------------------------------
__global__ __launch_bounds__(256, 4) void attn_fused(
    const float* __restrict__ qbuf, const float* __restrict__ kbuf,
    const _Float16* __restrict__ logw, const float* __restrict__ kcbuf,
    const float* __restrict__ bc, float* __restrict__ outp)
{
  __shared__ float qT[16][64];
  __shared__ __align__(16) _Float16 att[16][N_DIM];
  __shared__ float red[16][4];
  __shared__ float mrow[16], lrow[16];
  const int t  = threadIdx.x;
  const int g  = blockIdx.y;
  const int r0 = blockIdx.x * 16;
  {
    const int i = t >> 4, e4 = (t & 15) << 2;
    *(float4*)&qT[i][e4] = *(const float4*)(qbuf + (r0 + i) * FEAT + (g << 6) + e4);
  }
  __syncthreads();

  // phase 1: s[i][j] = q[i,:].k[n0+j,:]  for this thread's 4 n-columns
  const int n0 = t << 2;
  float s[16][4];
#pragma unroll
  for (int i = 0; i < 16; ++i) { s[i][0]=0.f; s[i][1]=0.f; s[i][2]=0.f; s[i][3]=0.f; }
  const float* kp = kbuf + (g << 6);
#pragma unroll 2
  for (int e4 = 0; e4 < 16; ++e4) {
    const float4 k0v = *(const float4*)(kp + (size_t)(n0+0)*FEAT + (e4<<2));
    const float4 k1v = *(const float4*)(kp + (size_t)(n0+1)*FEAT + (e4<<2));
    const float4 k2v = *(const float4*)(kp + (size_t)(n0+2)*FEAT + (e4<<2));
    const float4 k3v = *(const float4*)(kp + (size_t)(n0+3)*FEAT + (e4<<2));
#pragma unroll
    for (int i = 0; i < 16; ++i) {
      const float4 qv = *(const float4*)&qT[i][e4 << 2];
      s[i][0] += qv.x*k0v.x + qv.y*k0v.y + qv.z*k0v.z + qv.w*k0v.w;
      s[i][1] += qv.x*k1v.x + qv.y*k1v.y + qv.z*k1v.z + qv.w*k1v.w;
      s[i][2] += qv.x*k2v.x + qv.y*k2v.y + qv.z*k2v.z + qv.w*k2v.w;
      s[i][3] += qv.x*k3v.x + qv.y*k3v.y + qv.z*k3v.z + qv.w*k3v.w;
    }
  }
  // phase 1.5: scale + logw
#pragma unroll
  for (int i = 0; i < 16; ++i) {
    const h4 lw = *(const h4*)(logw + (size_t)((((r0+i) << 4) + g) << 10) + n0);
    s[i][0] = s[i][0]*0.125f + (float)lw.x;
    s[i][1] = s[i][1]*0.125f + (float)lw.y;
    s[i][2] = s[i][2]*0.125f + (float)lw.z;
    s[i][3] = s[i][3]*0.125f + (float)lw.w;
  }
  // phase 2: softmax stats (block-wide per-row reductions)
  const int wv = t >> 6, ln = t & 63;
#pragma unroll
  for (int i = 0; i < 16; ++i) {
    float m = fmaxf(fmaxf(s[i][0], s[i][1]), fmaxf(s[i][2], s[i][3]));
#pragma unroll
    for (int off = 32; off; off >>= 1) m = fmaxf(m, __shfl_xor(m, off));
    if (ln == 0) red[i][wv] = m;
  }
  __syncthreads();
  if (t < 16) mrow[t] = fmaxf(fmaxf(red[t][0], red[t][1]), fmaxf(red[t][2], red[t][3]));
  __syncthreads();
#pragma unroll
  for (int i = 0; i < 16; ++i) {
    const float mi = mrow[i];
    const float e0 = __expf(s[i][0]-mi), e1 = __expf(s[i][1]-mi);
    const float e2 = __expf(s[i][2]-mi), e3 = __expf(s[i][3]-mi);
    h4 ev; ev.x=(_Float16)e0; ev.y=(_Float16)e1; ev.z=(_Float16)e2; ev.w=(_Float16)e3;
    *(h4*)&att[i][n0] = ev;
    float sm = (e0 + e1) + (e2 + e3);
#pragma unroll
    for (int off = 32; off; off >>= 1) sm += __shfl_xor(sm, off);
    if (ln == 0) red[i][wv] = sm;
  }
  __syncthreads();
  if (t < 16) lrow[t] = (red[t][0] + red[t][1]) + (red[t][2] + red[t][3]);
  __syncthreads();

  // phase 3: out[r, g*64+o] = (sum_n att[r][n]*KC[g][n][o]) / l + bc
  const int rr = t >> 4, o0 = (t & 15) << 2;
  const float* kcp = kcbuf + ((size_t)g << 16);
  float ax = 0.f, ay = 0.f, az = 0.f, aw = 0.f;
#pragma unroll 2
  for (int n = 0; n < N_DIM; n += 4) {
    const h4 a4 = *(const h4*)&att[rr][n];
    const float a0=(float)a4.x, a1=(float)a4.y, a2=(float)a4.z, a3=(float)a4.w;
    const float4 c0v = *(const float4*)(kcp + ((n+0)<<6) + o0);
    const float4 c1v = *(const float4*)(kcp + ((n+1)<<6) + o0);
    const float4 c2v = *(const float4*)(kcp + ((n+2)<<6) + o0);
    const float4 c3v = *(const float4*)(kcp + ((n+3)<<6) + o0);
    ax += a0*c0v.x + a1*c1v.x + a2*c2v.x + a3*c3v.x;
    ay += a0*c0v.y + a1*c1v.y + a2*c2v.y + a3*c3v.y;
    az += a0*c0v.z + a1*c1v.z + a2*c2v.z + a3*c3v.z;
    aw += a0*c0v.w + a1*c1v.w + a2*c2v.w + a3*c3v.w;
  }
  const float inv = 1.0f / lrow[rr];
  const float4 bcv = *(const float4*)(bc + (g << 6) + o0);
  float4 o;
  o.x = ax*inv + bcv.x;
  o.y = ay*inv + bcv.y;
  o.z = az*inv + bcv.z;
  o.w = aw*inv + bcv.w;
  *(float4*)(outp + (size_t)(r0 + rr) * FEAT + (g << 6) + o0) = o;
}

// ---------------------------------------------------------------------------
extern "C" void kernel_launch(void* const* d_in, const int* in_sizes, int n_in,
                              void* d_out, int out_size, void* d_ws, size_t ws_size,
                              hipStream_t stream)
{
  const float* pe  = (const float*)d_in[0];
  const float* roi = (const float*)d_in[1];
  const float* Wq  = (const float*)d_in[2];
  const float* bq  = (const float*)d_in[3];
  const float* Wk  = (const float*)d_in[4];
  const float* bk  = (const float*)d_in[5];
  const float* Wp  = (const float*)d_in[6];
  const float* bp  = (const float*)d_in[7];
  const float* Wc  = (const float*)d_in[8];
  const float* bc  = (const float*)d_in[9];
  // d_in[10] = nongt_dim; shapes force nongt_dim == N_DIM == 1024 for the
  // reference broadcast to be valid, so it is not read on device.
  float* outp = (float*)d_out;

  char* ws = (char*)d_ws;
  float*     qbuf  = (float*)(ws);                       //  4 MB
  float*     kbuf  = (float*)(ws + ((size_t)4  << 20));  //  4 MB
  float*     kcbuf = (float*)(ws + ((size_t)8  << 20));  //  4 MB
  _Float16*  logw  = (_Float16*)(ws + ((size_t)12 << 20)); // 32 MB  (total 44 MB)

  qk_gemm<<<dim3(16, 16), 256, 0, stream>>>(roi, Wq, bq, Wk, bk, qbuf, kbuf);
  pos_log<<<2048, 256, 0, stream>>>(pe, Wp, bp, logw);
  kc_gemm<<<dim3(16, 16), 256, 0, stream>>>(roi, Wc, kcbuf);
  attn_fused<<<dim3(64, 16), 256, 0, stream>>>(qbuf, kbuf, logw, kcbuf, bc, outp);
}

// Round 2
// 453.069 us; speedup vs baseline: 1.5261x; 1.5261x over previous
//
#include <hip/hip_runtime.h>

#define R_DIM 1024
#define N_DIM 1024
#define FEAT  1024
#define EMB   64
#define GROUP 16
#define DG    64

struct __align__(8) h4 { _Float16 x, y, z, w; };

// ---------------------------------------------------------------------------
// K1: q = roi @ Wq^T + bq ; k = roi @ Wk^T + bk   (fused, shared A-tile)
// 64x64 tile, BK=16, 256 threads, 4x4 outputs per thread for each of q,k.
// Register prefetch hides global latency (grid = 256 blocks = 1 block/CU).
// ---------------------------------------------------------------------------
__global__ __launch_bounds__(256) void qk_gemm(
    const float* __restrict__ roi, const float* __restrict__ Wq,
    const float* __restrict__ bq,  const float* __restrict__ Wk,
    const float* __restrict__ bk,  float* __restrict__ qout,
    float* __restrict__ kout)
{
  __shared__ float aT[16][68];
  __shared__ float bqT[16][68];
  __shared__ float bkT[16][68];
  const int t  = threadIdx.x;
  const int r0 = blockIdx.x * 64, c0 = blockIdx.y * 64;
  const int lr = t >> 2, lk = (t & 3) << 2;
  const int ty = t >> 4, tx = t & 15;
  const float* ap  = roi + (r0 + lr) * FEAT + lk;
  const float* bqp = Wq  + (c0 + lr) * FEAT + lk;
  const float* bkp = Wk  + (c0 + lr) * FEAT + lk;
  float4 av  = *(const float4*)ap;
  float4 bqv = *(const float4*)bqp;
  float4 bkv = *(const float4*)bkp;
  float accq[4][4] = {}, acck[4][4] = {};
  for (int k0 = 0; k0 < FEAT; k0 += 16) {
    aT[lk+0][lr]=av.x;   aT[lk+1][lr]=av.y;   aT[lk+2][lr]=av.z;   aT[lk+3][lr]=av.w;
    bqT[lk+0][lr]=bqv.x; bqT[lk+1][lr]=bqv.y; bqT[lk+2][lr]=bqv.z; bqT[lk+3][lr]=bqv.w;
    bkT[lk+0][lr]=bkv.x; bkT[lk+1][lr]=bkv.y; bkT[lk+2][lr]=bkv.z; bkT[lk+3][lr]=bkv.w;
    __syncthreads();
    const bool more = (k0 + 16) < FEAT;
    float4 av_n, bqv_n, bkv_n;
    if (more) {
      av_n  = *(const float4*)(ap  + k0 + 16);
      bqv_n = *(const float4*)(bqp + k0 + 16);
      bkv_n = *(const float4*)(bkp + k0 + 16);
    }
#pragma unroll
    for (int kk = 0; kk < 16; ++kk) {
      const float4 a4 = *(const float4*)&aT[kk][ty << 2];
      const float4 q4 = *(const float4*)&bqT[kk][tx << 2];
      const float4 k4 = *(const float4*)&bkT[kk][tx << 2];
      const float ar[4] = {a4.x, a4.y, a4.z, a4.w};
      const float qr[4] = {q4.x, q4.y, q4.z, q4.w};
      const float kr[4] = {k4.x, k4.y, k4.z, k4.w};
#pragma unroll
      for (int i = 0; i < 4; ++i)
#pragma unroll
        for (int j = 0; j < 4; ++j) {
          accq[i][j] += ar[i] * qr[j];
          acck[i][j] += ar[i] * kr[j];
        }
    }
    __syncthreads();
    if (more) { av = av_n; bqv = bqv_n; bkv = bkv_n; }
  }
  const float4 bq4 = *(const float4*)(bq + c0 + (tx << 2));
  const float4 bk4 = *(const float4*)(bk + c0 + (tx << 2));
  const float bqr[4] = {bq4.x, bq4.y, bq4.z, bq4.w};
  const float bkr[4] = {bk4.x, bk4.y, bk4.z, bk4.w};
#pragma unroll
  for (int i = 0; i < 4; ++i) {
    float4 oq, ok;
    float* oqf = (float*)&oq; float* okf = (float*)&ok;
#pragma unroll
    for (int j = 0; j < 4; ++j) { oqf[j] = accq[i][j] + bqr[j]; okf[j] = acck[i][j] + bkr[j]; }
    const int row = r0 + (ty << 2) + i;
    *(float4*)(qout + row * FEAT + c0 + (tx << 2)) = oq;
    *(float4*)(kout + row * FEAT + c0 + (tx << 2)) = ok;
  }
}

// ---------------------------------------------------------------------------
// K2: logw[r,g,n] = log(max(relu(pos_emb[r,n,:].Wp[g,:] + bp[g]), 1e-6)), f16
// Each thread handles 2 n-rows (halves LDS Wp re-reads); memory-bound (256 MB).
// ---------------------------------------------------------------------------
__global__ __launch_bounds__(256) void pos_log(
    const float* __restrict__ pe, const float* __restrict__ Wp,
    const float* __restrict__ bp, _Float16* __restrict__ logw)
{
  __shared__ float wp[16][64];
  __shared__ float bps[16];
  const int t = threadIdx.x;
  ((float4*)&wp[0][0])[t] = ((const float4*)Wp)[t];   // 16*64 floats = 256 float4
  if (t < 16) bps[t] = bp[t];
  __syncthreads();
  const int bid = blockIdx.x;            // 2048 blocks
  const int r   = bid >> 1;
  const int na  = ((bid & 1) << 9) + t;  // n and n+256
  const int nb  = na + 256;
  const float* p0 = pe + (r * (size_t)N_DIM + na) * EMB;
  const float* p1 = pe + (r * (size_t)N_DIM + nb) * EMB;
  float acc0[16] = {}, acc1[16] = {};
#pragma unroll
  for (int e4 = 0; e4 < 16; ++e4) {
    const float4 x0 = *(const float4*)(p0 + (e4 << 2));
    const float4 x1 = *(const float4*)(p1 + (e4 << 2));
#pragma unroll
    for (int g = 0; g < 16; ++g) {
      const float4 w = *(const float4*)&wp[g][e4 << 2];
      acc0[g] += x0.x*w.x + x0.y*w.y + x0.z*w.z + x0.w*w.w;
      acc1[g] += x1.x*w.x + x1.y*w.y + x1.z*w.z + x1.w*w.w;
    }
  }
#pragma unroll
  for (int g = 0; g < 16; ++g) {
    const float v0 = fmaxf(acc0[g] + bps[g], 1e-6f);  // relu then clip == max(x,1e-6)
    const float v1 = fmaxf(acc1[g] + bps[g], 1e-6f);
    logw[(((r << 4) + g) << 10) + na] = (_Float16)__logf(v0);
    logw[(((r << 4) + g) << 10) + nb] = (_Float16)__logf(v1);
  }
}

// ---------------------------------------------------------------------------
// K3: KC[g][n][o] = sum_f roi[n][f] * Wc[g][o][f]   (no bias)
// Same tile structure as qk_gemm, single B.
// ---------------------------------------------------------------------------
__global__ __launch_bounds__(256) void kc_gemm(
    const float* __restrict__ roi, const float* __restrict__ Wc,
    float* __restrict__ kc)
{
  __shared__ float aT[16][68];
  __shared__ float bT[16][68];
  const int t  = threadIdx.x;
  const int n0 = blockIdx.x * 64;
  const int g  = blockIdx.y;
  const int lr = t >> 2, lk = (t & 3) << 2;
  const int ty = t >> 4, tx = t & 15;
  const float* ap  = roi + (n0 + lr) * FEAT + lk;
  const float* bp_ = Wc  + (g * DG + lr) * FEAT + lk;
  float4 av = *(const float4*)ap;
  float4 bv = *(const float4*)bp_;
  float acc[4][4] = {};
  for (int k0 = 0; k0 < FEAT; k0 += 16) {
    aT[lk+0][lr]=av.x; aT[lk+1][lr]=av.y; aT[lk+2][lr]=av.z; aT[lk+3][lr]=av.w;
    bT[lk+0][lr]=bv.x; bT[lk+1][lr]=bv.y; bT[lk+2][lr]=bv.z; bT[lk+3][lr]=bv.w;
    __syncthreads();
    const bool more = (k0 + 16) < FEAT;
    float4 av_n, bv_n;
    if (more) {
      av_n = *(const float4*)(ap  + k0 + 16);
      bv_n = *(const float4*)(bp_ + k0 + 16);
    }
#pragma unroll
    for (int kk = 0; kk < 16; ++kk) {
      const float4 a4 = *(const float4*)&aT[kk][ty << 2];
      const float4 b4 = *(const float4*)&bT[kk][tx << 2];
      const float ar[4] = {a4.x, a4.y, a4.z, a4.w};
      const float br[4] = {b4.x, b4.y, b4.z, b4.w};
#pragma unroll
      for (int i = 0; i < 4; ++i)
#pragma unroll
        for (int j = 0; j < 4; ++j) acc[i][j] += ar[i] * br[j];
    }
    __syncthreads();
    if (more) { av = av_n; bv = bv_n; }
  }
#pragma unroll
  for (int i = 0; i < 4; ++i) {
    float4 o; float* of = (float*)&o;
#pragma unroll
    for (int j = 0; j < 4; ++j) of[j] = acc[i][j];
    *(float4*)(kc + (size_t)((g << 10) + n0 + (ty << 2) + i) * DG + (tx << 2)) = o;
  }
}

// ---------------------------------------------------------------------------
// K4: fused attention. Block = (16 r-rows, one g). s = q.k^T*scale + logw,
// two-pass softmax (shuffle reduce), exp'd weights -> LDS f16, then att @ KC.
// NOTE: no min-waves in launch_bounds — (256,4) forced a 64-VGPR cap, which
// spilled s[16][4] to scratch => 1.06 GB of HBM writes per dispatch (R1).
// ---------------------------------------------------------------------------
__global__ __launch_bounds__(256) void attn_fused(
    const float* __restrict__ qbuf, const float* __restrict__ kbuf,
    const _Float16* __restrict__ logw, const float* __restrict__ kcbuf,
    const float* __restrict__ bc, float* __restrict__ outp)
{
  __shared__ float qT[16][64];
  __shared__ __align__(16) _Float16 att[16][N_DIM];
  __shared__ float red[16][4];
  __shared__ float mrow[16], lrow[16];
  const int t  = threadIdx.x;
  const int g  = blockIdx.y;
  const int r0 = blockIdx.x * 16;
  {
    const int i = t >> 4, e4 = (t & 15) << 2;
    *(float4*)&qT[i][e4] = *(const float4*)(qbuf + (r0 + i) * FEAT + (g << 6) + e4);
  }
  __syncthreads();

  // phase 1: s[i][j] = q[i,:].k[n0+j,:]  for this thread's 4 n-columns
  const int n0 = t << 2;
  float s[16][4];
#pragma unroll
  for (int i = 0; i < 16; ++i) { s[i][0]=0.f; s[i][1]=0.f; s[i][2]=0.f; s[i][3]=0.f; }
  const float* kp = kbuf + (g << 6);
#pragma unroll 2
  for (int e4 = 0; e4 < 16; ++e4) {
    const float4 k0v = *(const float4*)(kp + (size_t)(n0+0)*FEAT + (e4<<2));
    const float4 k1v = *(const float4*)(kp + (size_t)(n0+1)*FEAT + (e4<<2));
    const float4 k2v = *(const float4*)(kp + (size_t)(n0+2)*FEAT + (e4<<2));
    const float4 k3v = *(const float4*)(kp + (size_t)(n0+3)*FEAT + (e4<<2));
#pragma unroll
    for (int i = 0; i < 16; ++i) {
      const float4 qv = *(const float4*)&qT[i][e4 << 2];
      s[i][0] += qv.x*k0v.x + qv.y*k0v.y + qv.z*k0v.z + qv.w*k0v.w;
      s[i][1] += qv.x*k1v.x + qv.y*k1v.y + qv.z*k1v.z + qv.w*k1v.w;
      s[i][2] += qv.x*k2v.x + qv.y*k2v.y + qv.z*k2v.z + qv.w*k2v.w;
      s[i][3] += qv.x*k3v.x + qv.y*k3v.y + qv.z*k3v.z + qv.w*k3v.w;
    }
  }
  // phase 1.5: scale + logw
#pragma unroll
  for (int i = 0; i < 16; ++i) {
    const h4 lw = *(const h4*)(logw + (size_t)((((r0+i) << 4) + g) << 10) + n0);
    s[i][0] = s[i][0]*0.125f + (float)lw.x;
    s[i][1] = s[i][1]*0.125f + (float)lw.y;
    s[i][2] = s[i][2]*0.125f + (float)lw.z;
    s[i][3] = s[i][3]*0.125f + (float)lw.w;
  }
  // phase 2: softmax stats (block-wide per-row reductions)
  const int wv = t >> 6, ln = t & 63;
#pragma unroll
  for (int i = 0; i < 16; ++i) {
    float m = fmaxf(fmaxf(s[i][0], s[i][1]), fmaxf(s[i][2], s[i][3]));
#pragma unroll
    for (int off = 32; off; off >>= 1) m = fmaxf(m, __shfl_xor(m, off));
    if (ln == 0) red[i][wv] = m;
  }
  __syncthreads();
  if (t < 16) mrow[t] = fmaxf(fmaxf(red[t][0], red[t][1]), fmaxf(red[t][2], red[t][3]));
  __syncthreads();
#pragma unroll
  for (int i = 0; i < 16; ++i) {
    const float mi = mrow[i];
    const float e0 = __expf(s[i][0]-mi), e1 = __expf(s[i][1]-mi);
    const float e2 = __expf(s[i][2]-mi), e3 = __expf(s[i][3]-mi);
    h4 ev; ev.x=(_Float16)e0; ev.y=(_Float16)e1; ev.z=(_Float16)e2; ev.w=(_Float16)e3;
    *(h4*)&att[i][n0] = ev;
    float sm = (e0 + e1) + (e2 + e3);
#pragma unroll
    for (int off = 32; off; off >>= 1) sm += __shfl_xor(sm, off);
    if (ln == 0) red[i][wv] = sm;
  }
  __syncthreads();
  if (t < 16) lrow[t] = (red[t][0] + red[t][1]) + (red[t][2] + red[t][3]);
  __syncthreads();

  // phase 3: out[r, g*64+o] = (sum_n att[r][n]*KC[g][n][o]) / l + bc
  const int rr = t >> 4, o0 = (t & 15) << 2;
  const float* kcp = kcbuf + ((size_t)g << 16);
  float ax = 0.f, ay = 0.f, az = 0.f, aw = 0.f;
#pragma unroll 2
  for (int n = 0; n < N_DIM; n += 4) {
    const h4 a4 = *(const h4*)&att[rr][n];
    const float a0=(float)a4.x, a1=(float)a4.y, a2=(float)a4.z, a3=(float)a4.w;
    const float4 c0v = *(const float4*)(kcp + ((n+0)<<6) + o0);
    const float4 c1v = *(const float4*)(kcp + ((n+1)<<6) + o0);
    const float4 c2v = *(const float4*)(kcp + ((n+2)<<6) + o0);
    const float4 c3v = *(const float4*)(kcp + ((n+3)<<6) + o0);
    ax += a0*c0v.x + a1*c1v.x + a2*c2v.x + a3*c3v.x;
    ay += a0*c0v.y + a1*c1v.y + a2*c2v.y + a3*c3v.y;
    az += a0*c0v.z + a1*c1v.z + a2*c2v.z + a3*c3v.z;
    aw += a0*c0v.w + a1*c1v.w + a2*c2v.w + a3*c3v.w;
  }
  const float inv = 1.0f / lrow[rr];
  const float4 bcv = *(const float4*)(bc + (g << 6) + o0);
  float4 o;
  o.x = ax*inv + bcv.x;
  o.y = ay*inv + bcv.y;
  o.z = az*inv + bcv.z;
  o.w = aw*inv + bcv.w;
  *(float4*)(outp + (size_t)(r0 + rr) * FEAT + (g << 6) + o0) = o;
}

// ---------------------------------------------------------------------------
extern "C" void kernel_launch(void* const* d_in, const int* in_sizes, int n_in,
                              void* d_out, int out_size, void* d_ws, size_t ws_size,
                              hipStream_t stream)
{
  const float* pe  = (const float*)d_in[0];
  const float* roi = (const float*)d_in[1];
  const float* Wq  = (const float*)d_in[2];
  const float* bq  = (const float*)d_in[3];
  const float* Wk  = (const float*)d_in[4];
  const float* bk  = (const float*)d_in[5];
  const float* Wp  = (const float*)d_in[6];
  const float* bp  = (const float*)d_in[7];
  const float* Wc  = (const float*)d_in[8];
  const float* bc  = (const float*)d_in[9];
  // d_in[10] = nongt_dim; shapes force nongt_dim == N_DIM == 1024 for the
  // reference broadcast to be valid, so it is not read on device.
  float* outp = (float*)d_out;

  char* ws = (char*)d_ws;
  float*     qbuf  = (float*)(ws);                       //  4 MB
  float*     kbuf  = (float*)(ws + ((size_t)4  << 20));  //  4 MB
  float*     kcbuf = (float*)(ws + ((size_t)8  << 20));  //  4 MB
  _Float16*  logw  = (_Float16*)(ws + ((size_t)12 << 20)); // 32 MB  (total 44 MB)

  qk_gemm<<<dim3(16, 16), 256, 0, stream>>>(roi, Wq, bq, Wk, bk, qbuf, kbuf);
  pos_log<<<2048, 256, 0, stream>>>(pe, Wp, bp, logw);
  kc_gemm<<<dim3(16, 16), 256, 0, stream>>>(roi, Wc, kcbuf);
  attn_fused<<<dim3(64, 16), 256, 0, stream>>>(qbuf, kbuf, logw, kcbuf, bc, outp);
}

// Round 3
// 364.483 us; speedup vs baseline: 1.8970x; 1.2430x over previous
//
#include <hip/hip_runtime.h>

#define R_DIM 1024
#define N_DIM 1024
#define FEAT  1024
#define EMB   64
#define GROUP 16
#define DG    64

struct __align__(8) h4 { _Float16 x, y, z, w; };

// ---------------------------------------------------------------------------
// K1: q = roi @ Wq^T + bq  (row-major [r][f])
//     kT[g][e][n] = (roi @ Wk^T + bk) transposed  (for coalesced attn reads)
// 64x64 tile, BK=16, 256 threads, 4x4 outputs per thread for each of q,k.
// ---------------------------------------------------------------------------
__global__ __launch_bounds__(256) void qk_gemm(
    const float* __restrict__ roi, const float* __restrict__ Wq,
    const float* __restrict__ bq,  const float* __restrict__ Wk,
    const float* __restrict__ bk,  float* __restrict__ qout,
    float* __restrict__ kT)
{
  __shared__ float aT[16][68];
  __shared__ float bqT[16][68];
  __shared__ float bkT[16][68];
  const int t  = threadIdx.x;
  const int r0 = blockIdx.x * 64, c0 = blockIdx.y * 64;
  const int lr = t >> 2, lk = (t & 3) << 2;
  const int ty = t >> 4, tx = t & 15;
  const float* ap  = roi + (r0 + lr) * FEAT + lk;
  const float* bqp = Wq  + (c0 + lr) * FEAT + lk;
  const float* bkp = Wk  + (c0 + lr) * FEAT + lk;
  float4 av  = *(const float4*)ap;
  float4 bqv = *(const float4*)bqp;
  float4 bkv = *(const float4*)bkp;
  float accq[4][4] = {}, acck[4][4] = {};
  for (int k0 = 0; k0 < FEAT; k0 += 16) {
    aT[lk+0][lr]=av.x;   aT[lk+1][lr]=av.y;   aT[lk+2][lr]=av.z;   aT[lk+3][lr]=av.w;
    bqT[lk+0][lr]=bqv.x; bqT[lk+1][lr]=bqv.y; bqT[lk+2][lr]=bqv.z; bqT[lk+3][lr]=bqv.w;
    bkT[lk+0][lr]=bkv.x; bkT[lk+1][lr]=bkv.y; bkT[lk+2][lr]=bkv.z; bkT[lk+3][lr]=bkv.w;
    __syncthreads();
    const bool more = (k0 + 16) < FEAT;
    float4 av_n, bqv_n, bkv_n;
    if (more) {
      av_n  = *(const float4*)(ap  + k0 + 16);
      bqv_n = *(const float4*)(bqp + k0 + 16);
      bkv_n = *(const float4*)(bkp + k0 + 16);
    }
#pragma unroll
    for (int kk = 0; kk < 16; ++kk) {
      const float4 a4 = *(const float4*)&aT[kk][ty << 2];
      const float4 q4 = *(const float4*)&bqT[kk][tx << 2];
      const float4 k4 = *(const float4*)&bkT[kk][tx << 2];
      const float ar[4] = {a4.x, a4.y, a4.z, a4.w};
      const float qr[4] = {q4.x, q4.y, q4.z, q4.w};
      const float kr[4] = {k4.x, k4.y, k4.z, k4.w};
#pragma unroll
      for (int i = 0; i < 4; ++i)
#pragma unroll
        for (int j = 0; j < 4; ++j) {
          accq[i][j] += ar[i] * qr[j];
          acck[i][j] += ar[i] * kr[j];
        }
    }
    __syncthreads();
    if (more) { av = av_n; bqv = bqv_n; bkv = bkv_n; }
  }
  const float4 bq4 = *(const float4*)(bq + c0 + (tx << 2));
  const float4 bk4 = *(const float4*)(bk + c0 + (tx << 2));
  const float bqr[4] = {bq4.x, bq4.y, bq4.z, bq4.w};
  const float bkr[4] = {bk4.x, bk4.y, bk4.z, bk4.w};
#pragma unroll
  for (int i = 0; i < 4; ++i) {
    float4 oq; float* oqf = (float*)&oq;
#pragma unroll
    for (int j = 0; j < 4; ++j) oqf[j] = accq[i][j] + bqr[j];
    const int row = r0 + (ty << 2) + i;
    *(float4*)(qout + row * FEAT + c0 + (tx << 2)) = oq;
  }
  // k stored transposed: kT[f][n] (f = g*64+e), n-runs of 4 are contiguous;
  // within a wave the 4 ty-lanes complete each 64B line.
#pragma unroll
  for (int j = 0; j < 4; ++j) {
    float4 ok;
    ok.x = acck[0][j] + bkr[j];
    ok.y = acck[1][j] + bkr[j];
    ok.z = acck[2][j] + bkr[j];
    ok.w = acck[3][j] + bkr[j];
    const int f = c0 + (tx << 2) + j;
    *(float4*)(kT + ((size_t)f << 10) + r0 + (ty << 2)) = ok;
  }
}

// ---------------------------------------------------------------------------
// K2: logw[r,g,n] = log(max(relu(pos_emb[r,n,:].Wp[g,:] + bp[g]), 1e-6)), f16
// ---------------------------------------------------------------------------
__global__ __launch_bounds__(256) void pos_log(
    const float* __restrict__ pe, const float* __restrict__ Wp,
    const float* __restrict__ bp, _Float16* __restrict__ logw)
{
  __shared__ float wp[16][64];
  __shared__ float bps[16];
  const int t = threadIdx.x;
  ((float4*)&wp[0][0])[t] = ((const float4*)Wp)[t];   // 16*64 floats = 256 float4
  if (t < 16) bps[t] = bp[t];
  __syncthreads();
  const int bid = blockIdx.x;            // 2048 blocks
  const int r   = bid >> 1;
  const int na  = ((bid & 1) << 9) + t;  // n and n+256
  const int nb  = na + 256;
  const float* p0 = pe + (r * (size_t)N_DIM + na) * EMB;
  const float* p1 = pe + (r * (size_t)N_DIM + nb) * EMB;
  float acc0[16] = {}, acc1[16] = {};
#pragma unroll
  for (int e4 = 0; e4 < 16; ++e4) {
    const float4 x0 = *(const float4*)(p0 + (e4 << 2));
    const float4 x1 = *(const float4*)(p1 + (e4 << 2));
#pragma unroll
    for (int g = 0; g < 16; ++g) {
      const float4 w = *(const float4*)&wp[g][e4 << 2];
      acc0[g] += x0.x*w.x + x0.y*w.y + x0.z*w.z + x0.w*w.w;
      acc1[g] += x1.x*w.x + x1.y*w.y + x1.z*w.z + x1.w*w.w;
    }
  }
#pragma unroll
  for (int g = 0; g < 16; ++g) {
    const float v0 = fmaxf(acc0[g] + bps[g], 1e-6f);  // relu then clip == max(x,1e-6)
    const float v1 = fmaxf(acc1[g] + bps[g], 1e-6f);
    logw[(((r << 4) + g) << 10) + na] = (_Float16)__logf(v0);
    logw[(((r << 4) + g) << 10) + nb] = (_Float16)__logf(v1);
  }
}

// ---------------------------------------------------------------------------
// K3: KC[g][n][o] = sum_f roi[n][f] * Wc[g][o][f]   (no bias)
// ---------------------------------------------------------------------------
__global__ __launch_bounds__(256) void kc_gemm(
    const float* __restrict__ roi, const float* __restrict__ Wc,
    float* __restrict__ kc)
{
  __shared__ float aT[16][68];
  __shared__ float bT[16][68];
  const int t  = threadIdx.x;
  const int n0 = blockIdx.x * 64;
  const int g  = blockIdx.y;
  const int lr = t >> 2, lk = (t & 3) << 2;
  const int ty = t >> 4, tx = t & 15;
  const float* ap  = roi + (n0 + lr) * FEAT + lk;
  const float* bp_ = Wc  + (g * DG + lr) * FEAT + lk;
  float4 av = *(const float4*)ap;
  float4 bv = *(const float4*)bp_;
  float acc[4][4] = {};
  for (int k0 = 0; k0 < FEAT; k0 += 16) {
    aT[lk+0][lr]=av.x; aT[lk+1][lr]=av.y; aT[lk+2][lr]=av.z; aT[lk+3][lr]=av.w;
    bT[lk+0][lr]=bv.x; bT[lk+1][lr]=bv.y; bT[lk+2][lr]=bv.z; bT[lk+3][lr]=bv.w;
    __syncthreads();
    const bool more = (k0 + 16) < FEAT;
    float4 av_n, bv_n;
    if (more) {
      av_n = *(const float4*)(ap  + k0 + 16);
      bv_n = *(const float4*)(bp_ + k0 + 16);
    }
#pragma unroll
    for (int kk = 0; kk < 16; ++kk) {
      const float4 a4 = *(const float4*)&aT[kk][ty << 2];
      const float4 b4 = *(const float4*)&bT[kk][tx << 2];
      const float ar[4] = {a4.x, a4.y, a4.z, a4.w};
      const float br[4] = {b4.x, b4.y, b4.z, b4.w};
#pragma unroll
      for (int i = 0; i < 4; ++i)
#pragma unroll
        for (int j = 0; j < 4; ++j) acc[i][j] += ar[i] * br[j];
    }
    __syncthreads();
    if (more) { av = av_n; bv = bv_n; }
  }
#pragma unroll
  for (int i = 0; i < 4; ++i) {
    float4 o; float* of = (float*)&o;
#pragma unroll
    for (int j = 0; j < 4; ++j) of[j] = acc[i][j];
    *(float4*)(kc + (size_t)((g << 10) + n0 + (ty << 2) + i) * DG + (tx << 2)) = o;
  }
}

// ---------------------------------------------------------------------------
// K4: fused attention. Block = (16 r-rows, one g). s = q.kT*scale + logw,
// two-pass softmax (shuffle reduce), exp'd weights -> LDS f16, then att @ KC.
// kT reads are coalesced (lane = n); att rows padded (+8 f16) so the 4
// rr-groups of a wave hit 4 distinct banks (R2: 2.1M bank conflicts).
// ---------------------------------------------------------------------------
#define ATT_LD (N_DIM + 8)
__global__ __launch_bounds__(256) void attn_fused(
    const float* __restrict__ qbuf, const float* __restrict__ kT,
    const _Float16* __restrict__ logw, const float* __restrict__ kcbuf,
    const float* __restrict__ bc, float* __restrict__ outp)
{
  __shared__ float qT[16][64];
  __shared__ __align__(16) _Float16 att[16][ATT_LD];
  __shared__ float red[16][4];
  __shared__ float mrow[16], lrow[16];
  const int t  = threadIdx.x;
  const int g  = blockIdx.y;
  const int r0 = blockIdx.x * 16;
  {
    const int i = t >> 4, e4 = (t & 15) << 2;
    *(float4*)&qT[i][e4] = *(const float4*)(qbuf + (r0 + i) * FEAT + (g << 6) + e4);
  }
  __syncthreads();

  // phase 1: s[i][j] = sum_e q[i][e] * kT[e][n0+j]   (coalesced kT reads)
  const int n0 = t << 2;
  float s[16][4];
#pragma unroll
  for (int i = 0; i < 16; ++i) { s[i][0]=0.f; s[i][1]=0.f; s[i][2]=0.f; s[i][3]=0.f; }
  const float* ktp = kT + ((size_t)g << 16) + n0;
#pragma unroll 4
  for (int e4 = 0; e4 < 16; ++e4) {
    const float4 k0v = *(const float4*)(ktp + (((e4<<2)+0) << 10));
    const float4 k1v = *(const float4*)(ktp + (((e4<<2)+1) << 10));
    const float4 k2v = *(const float4*)(ktp + (((e4<<2)+2) << 10));
    const float4 k3v = *(const float4*)(ktp + (((e4<<2)+3) << 10));
#pragma unroll
    for (int i = 0; i < 16; ++i) {
      const float4 qv = *(const float4*)&qT[i][e4 << 2];
      s[i][0] += qv.x*k0v.x + qv.y*k1v.x + qv.z*k2v.x + qv.w*k3v.x;
      s[i][1] += qv.x*k0v.y + qv.y*k1v.y + qv.z*k2v.y + qv.w*k3v.y;
      s[i][2] += qv.x*k0v.z + qv.y*k1v.z + qv.z*k2v.z + qv.w*k3v.z;
      s[i][3] += qv.x*k0v.w + qv.y*k1v.w + qv.z*k2v.w + qv.w*k3v.w;
    }
  }
  // phase 1.5: scale + logw
#pragma unroll
  for (int i = 0; i < 16; ++i) {
    const h4 lw = *(const h4*)(logw + (size_t)((((r0+i) << 4) + g) << 10) + n0);
    s[i][0] = s[i][0]*0.125f + (float)lw.x;
    s[i][1] = s[i][1]*0.125f + (float)lw.y;
    s[i][2] = s[i][2]*0.125f + (float)lw.z;
    s[i][3] = s[i][3]*0.125f + (float)lw.w;
  }
  // phase 2: softmax stats (block-wide per-row reductions)
  const int wv = t >> 6, ln = t & 63;
#pragma unroll
  for (int i = 0; i < 16; ++i) {
    float m = fmaxf(fmaxf(s[i][0], s[i][1]), fmaxf(s[i][2], s[i][3]));
#pragma unroll
    for (int off = 32; off; off >>= 1) m = fmaxf(m, __shfl_xor(m, off));
    if (ln == 0) red[i][wv] = m;
  }
  __syncthreads();
  if (t < 16) mrow[t] = fmaxf(fmaxf(red[t][0], red[t][1]), fmaxf(red[t][2], red[t][3]));
  __syncthreads();
#pragma unroll
  for (int i = 0; i < 16; ++i) {
    const float mi = mrow[i];
    const float e0 = __expf(s[i][0]-mi), e1 = __expf(s[i][1]-mi);
    const float e2 = __expf(s[i][2]-mi), e3 = __expf(s[i][3]-mi);
    h4 ev; ev.x=(_Float16)e0; ev.y=(_Float16)e1; ev.z=(_Float16)e2; ev.w=(_Float16)e3;
    *(h4*)&att[i][n0] = ev;
    float sm = (e0 + e1) + (e2 + e3);
#pragma unroll
    for (int off = 32; off; off >>= 1) sm += __shfl_xor(sm, off);
    if (ln == 0) red[i][wv] = sm;
  }
  __syncthreads();
  if (t < 16) lrow[t] = (red[t][0] + red[t][1]) + (red[t][2] + red[t][3]);
  __syncthreads();

  // phase 3: out[r, g*64+o] = (sum_n att[r][n]*KC[g][n][o]) / l + bc
  const int rr = t >> 4, o0 = (t & 15) << 2;
  const float* kcp = kcbuf + ((size_t)g << 16);
  float ax = 0.f, ay = 0.f, az = 0.f, aw = 0.f;
#pragma unroll 2
  for (int n = 0; n < N_DIM; n += 4) {
    const h4 a4 = *(const h4*)&att[rr][n];
    const float a0=(float)a4.x, a1=(float)a4.y, a2=(float)a4.z, a3=(float)a4.w;
    const float4 c0v = *(const float4*)(kcp + ((n+0)<<6) + o0);
    const float4 c1v = *(const float4*)(kcp + ((n+1)<<6) + o0);
    const float4 c2v = *(const float4*)(kcp + ((n+2)<<6) + o0);
    const float4 c3v = *(const float4*)(kcp + ((n+3)<<6) + o0);
    ax += a0*c0v.x + a1*c1v.x + a2*c2v.x + a3*c3v.x;
    ay += a0*c0v.y + a1*c1v.y + a2*c2v.y + a3*c3v.y;
    az += a0*c0v.z + a1*c1v.z + a2*c2v.z + a3*c3v.z;
    aw += a0*c0v.w + a1*c1v.w + a2*c2v.w + a3*c3v.w;
  }
  const float inv = 1.0f / lrow[rr];
  const float4 bcv = *(const float4*)(bc + (g << 6) + o0);
  float4 o;
  o.x = ax*inv + bcv.x;
  o.y = ay*inv + bcv.y;
  o.z = az*inv + bcv.z;
  o.w = aw*inv + bcv.w;
  *(float4*)(outp + (size_t)(r0 + rr) * FEAT + (g << 6) + o0) = o;
}

// ---------------------------------------------------------------------------
extern "C" void kernel_launch(void* const* d_in, const int* in_sizes, int n_in,
                              void* d_out, int out_size, void* d_ws, size_t ws_size,
                              hipStream_t stream)
{
  const float* pe  = (const float*)d_in[0];
  const float* roi = (const float*)d_in[1];
  const float* Wq  = (const float*)d_in[2];
  const float* bq  = (const float*)d_in[3];
  const float* Wk  = (const float*)d_in[4];
  const float* bk  = (const float*)d_in[5];
  const float* Wp  = (const float*)d_in[6];
  const float* bp  = (const float*)d_in[7];
  const float* Wc  = (const float*)d_in[8];
  const float* bc  = (const float*)d_in[9];
  float* outp = (float*)d_out;

  char* ws = (char*)d_ws;
  float*     qbuf  = (float*)(ws);                         //  4 MB
  float*     kTbuf = (float*)(ws + ((size_t)4  << 20));    //  4 MB [g][e][n]
  float*     kcbuf = (float*)(ws + ((size_t)8  << 20));    //  4 MB
  _Float16*  logw  = (_Float16*)(ws + ((size_t)12 << 20)); // 32 MB  (total 44 MB)

  qk_gemm<<<dim3(16, 16), 256, 0, stream>>>(roi, Wq, bq, Wk, bk, qbuf, kTbuf);
  pos_log<<<2048, 256, 0, stream>>>(pe, Wp, bp, logw);
  kc_gemm<<<dim3(16, 16), 256, 0, stream>>>(roi, Wc, kcbuf);
  attn_fused<<<dim3(64, 16), 256, 0, stream>>>(qbuf, kTbuf, logw, kcbuf, bc, outp);
}

// Round 4
// 235.787 us; speedup vs baseline: 2.9324x; 1.5458x over previous
//
#include <hip/hip_runtime.h>

#define R_DIM 1024
#define N_DIM 1024
#define FEAT  1024
#define EMB   64
#define GROUP 16
#define DG    64

typedef _Float16 half8  __attribute__((ext_vector_type(8)));
typedef _Float16 half4v __attribute__((ext_vector_type(4)));
typedef float    f32x4  __attribute__((ext_vector_type(4)));

// ---------------------------------------------------------------------------
// K1: qh = f16(roi @ Wq^T + bq), kh = f16(roi @ Wk^T + bk), both row-major
// [1024][1024] f16. fp32 accumulate in 64x64 tiles (BK=16), f16 on store only.
// ---------------------------------------------------------------------------
__global__ __launch_bounds__(256) void qk_gemm(
    const float* __restrict__ roi, const float* __restrict__ Wq,
    const float* __restrict__ bq,  const float* __restrict__ Wk,
    const float* __restrict__ bk,  _Float16* __restrict__ qh,
    _Float16* __restrict__ kh)
{
  __shared__ float aT[16][68];
  __shared__ float bqT[16][68];
  __shared__ float bkT[16][68];
  const int t  = threadIdx.x;
  const int r0 = blockIdx.x * 64, c0 = blockIdx.y * 64;
  const int lr = t >> 2, lk = (t & 3) << 2;
  const int ty = t >> 4, tx = t & 15;
  const float* ap  = roi + (r0 + lr) * FEAT + lk;
  const float* bqp = Wq  + (c0 + lr) * FEAT + lk;
  const float* bkp = Wk  + (c0 + lr) * FEAT + lk;
  float4 av  = *(const float4*)ap;
  float4 bqv = *(const float4*)bqp;
  float4 bkv = *(const float4*)bkp;
  float accq[4][4] = {}, acck[4][4] = {};
  for (int k0 = 0; k0 < FEAT; k0 += 16) {
    aT[lk+0][lr]=av.x;   aT[lk+1][lr]=av.y;   aT[lk+2][lr]=av.z;   aT[lk+3][lr]=av.w;
    bqT[lk+0][lr]=bqv.x; bqT[lk+1][lr]=bqv.y; bqT[lk+2][lr]=bqv.z; bqT[lk+3][lr]=bqv.w;
    bkT[lk+0][lr]=bkv.x; bkT[lk+1][lr]=bkv.y; bkT[lk+2][lr]=bkv.z; bkT[lk+3][lr]=bkv.w;
    __syncthreads();
    const bool more = (k0 + 16) < FEAT;
    float4 av_n, bqv_n, bkv_n;
    if (more) {
      av_n  = *(const float4*)(ap  + k0 + 16);
      bqv_n = *(const float4*)(bqp + k0 + 16);
      bkv_n = *(const float4*)(bkp + k0 + 16);
    }
#pragma unroll
    for (int kk = 0; kk < 16; ++kk) {
      const float4 a4 = *(const float4*)&aT[kk][ty << 2];
      const float4 q4 = *(const float4*)&bqT[kk][tx << 2];
      const float4 k4 = *(const float4*)&bkT[kk][tx << 2];
      const float ar[4] = {a4.x, a4.y, a4.z, a4.w};
      const float qr[4] = {q4.x, q4.y, q4.z, q4.w};
      const float kr[4] = {k4.x, k4.y, k4.z, k4.w};
#pragma unroll
      for (int i = 0; i < 4; ++i)
#pragma unroll
        for (int j = 0; j < 4; ++j) {
          accq[i][j] += ar[i] * qr[j];
          acck[i][j] += ar[i] * kr[j];
        }
    }
    __syncthreads();
    if (more) { av = av_n; bqv = bqv_n; bkv = bkv_n; }
  }
  const float4 bq4 = *(const float4*)(bq + c0 + (tx << 2));
  const float4 bk4 = *(const float4*)(bk + c0 + (tx << 2));
  const float bqr[4] = {bq4.x, bq4.y, bq4.z, bq4.w};
  const float bkr[4] = {bk4.x, bk4.y, bk4.z, bk4.w};
#pragma unroll
  for (int i = 0; i < 4; ++i) {
    half4v oq, ok;
#pragma unroll
    for (int j = 0; j < 4; ++j) {
      oq[j] = (_Float16)(accq[i][j] + bqr[j]);
      ok[j] = (_Float16)(acck[i][j] + bkr[j]);
    }
    const int row = r0 + (ty << 2) + i;
    *(half4v*)(qh + (size_t)row * FEAT + c0 + (tx << 2)) = oq;
    *(half4v*)(kh + (size_t)row * FEAT + c0 + (tx << 2)) = ok;
  }
}

// ---------------------------------------------------------------------------
// K2: logw[r,g,n] = log(max(relu(pos_emb[r,n,:].Wp[g,:] + bp[g]), 1e-6)), f16
// ---------------------------------------------------------------------------
__global__ __launch_bounds__(256) void pos_log(
    const float* __restrict__ pe, const float* __restrict__ Wp,
    const float* __restrict__ bp, _Float16* __restrict__ logw)
{
  __shared__ float wp[16][64];
  __shared__ float bps[16];
  const int t = threadIdx.x;
  ((float4*)&wp[0][0])[t] = ((const float4*)Wp)[t];
  if (t < 16) bps[t] = bp[t];
  __syncthreads();
  const int bid = blockIdx.x;            // 2048 blocks
  const int r   = bid >> 1;
  const int na  = ((bid & 1) << 9) + t;
  const int nb  = na + 256;
  const float* p0 = pe + (r * (size_t)N_DIM + na) * EMB;
  const float* p1 = pe + (r * (size_t)N_DIM + nb) * EMB;
  float acc0[16] = {}, acc1[16] = {};
#pragma unroll
  for (int e4 = 0; e4 < 16; ++e4) {
    const float4 x0 = *(const float4*)(p0 + (e4 << 2));
    const float4 x1 = *(const float4*)(p1 + (e4 << 2));
#pragma unroll
    for (int g = 0; g < 16; ++g) {
      const float4 w = *(const float4*)&wp[g][e4 << 2];
      acc0[g] += x0.x*w.x + x0.y*w.y + x0.z*w.z + x0.w*w.w;
      acc1[g] += x1.x*w.x + x1.y*w.y + x1.z*w.z + x1.w*w.w;
    }
  }
#pragma unroll
  for (int g = 0; g < 16; ++g) {
    const float v0 = fmaxf(acc0[g] + bps[g], 1e-6f);
    const float v1 = fmaxf(acc1[g] + bps[g], 1e-6f);
    logw[(size_t)(((r << 4) + g) << 10) + na] = (_Float16)__logf(v0);
    logw[(size_t)(((r << 4) + g) << 10) + nb] = (_Float16)__logf(v1);
  }
}

// ---------------------------------------------------------------------------
// K3: kct[g][o][n] = f16( sum_f Wc[g][o][f] * roi[n][f] )  (KC transposed so
// PV B-fragments are contiguous 16B loads). A = Wc[g] (rows o), B = roi (rows n).
// ---------------------------------------------------------------------------
__global__ __launch_bounds__(256) void kc_gemm(
    const float* __restrict__ roi, const float* __restrict__ Wc,
    _Float16* __restrict__ kct)
{
  __shared__ float aT[16][68];
  __shared__ float bT[16][68];
  const int t  = threadIdx.x;
  const int n0 = blockIdx.x * 64;
  const int g  = blockIdx.y;
  const int lr = t >> 2, lk = (t & 3) << 2;
  const int ty = t >> 4, tx = t & 15;
  const float* ap  = Wc  + (size_t)(g * DG + lr) * FEAT + lk;  // o-rows
  const float* bp_ = roi + (size_t)(n0 + lr) * FEAT + lk;      // n-rows
  float4 av = *(const float4*)ap;
  float4 bv = *(const float4*)bp_;
  float acc[4][4] = {};
  for (int k0 = 0; k0 < FEAT; k0 += 16) {
    aT[lk+0][lr]=av.x; aT[lk+1][lr]=av.y; aT[lk+2][lr]=av.z; aT[lk+3][lr]=av.w;
    bT[lk+0][lr]=bv.x; bT[lk+1][lr]=bv.y; bT[lk+2][lr]=bv.z; bT[lk+3][lr]=bv.w;
    __syncthreads();
    const bool more = (k0 + 16) < FEAT;
    float4 av_n, bv_n;
    if (more) {
      av_n = *(const float4*)(ap  + k0 + 16);
      bv_n = *(const float4*)(bp_ + k0 + 16);
    }
#pragma unroll
    for (int kk = 0; kk < 16; ++kk) {
      const float4 a4 = *(const float4*)&aT[kk][ty << 2];
      const float4 b4 = *(const float4*)&bT[kk][tx << 2];
      const float ar[4] = {a4.x, a4.y, a4.z, a4.w};
      const float br[4] = {b4.x, b4.y, b4.z, b4.w};
#pragma unroll
      for (int i = 0; i < 4; ++i)
#pragma unroll
        for (int j = 0; j < 4; ++j) acc[i][j] += ar[i] * br[j];
    }
    __syncthreads();
    if (more) { av = av_n; bv = bv_n; }
  }
  // acc[i][j]: o = ty*4+i, n = n0+tx*4+j  ->  kct[(g*64+o)*1024 + n]
#pragma unroll
  for (int i = 0; i < 4; ++i) {
    half4v o4;
#pragma unroll
    for (int j = 0; j < 4; ++j) o4[j] = (_Float16)acc[i][j];
    *(half4v*)(kct + (size_t)((g << 6) + (ty << 2) + i) * N_DIM + n0 + (tx << 2)) = o4;
  }
}

// ---------------------------------------------------------------------------
// K4: MFMA attention. Block = 16 q-rows x one g, 4 waves; wave w owns n-strip
// [w*256, w*256+256). QK^T and PV via v_mfma_f32_16x16x32_f16 (fp32 accum).
// Fragment maps (CDNA): A row=lane&15, k=(lane>>4)*8+j ; B col=lane&15, same k;
// C/D col=lane&15, row=(lane>>4)*4+reg (m89-verified).
// P staged in LDS f16, rows padded to 1032 (2064B: 16B-aligned, bank-uniform).
// ---------------------------------------------------------------------------
#define PLD 1032
__global__ __launch_bounds__(256) void attn_mfma(
    const _Float16* __restrict__ qh, const _Float16* __restrict__ kh,
    const _Float16* __restrict__ logw, const _Float16* __restrict__ kct,
    const float* __restrict__ bc, float* __restrict__ outp)
{
  __shared__ __align__(16) _Float16 P[16][PLD];   // 33,024 B
  __shared__ float Ored[4][16][68];               // 17,408 B
  __shared__ float redm[4][16];
  __shared__ float redl[4][16];

  const int t   = threadIdx.x;
  const int w   = t >> 6;
  const int l   = t & 63;
  const int q16 = l & 15;          // A-row / B-col / D-col
  const int q4  = l >> 4;          // k-quarter / D-row-quarter
  const int g   = blockIdx.y;
  const int r0  = blockIdx.x << 4;
  const int nbase = w << 8;

  // ---- QK^T: S[16 tiles], each 16x16 over this wave's 256 n ----
  const half8* qp = (const half8*)(qh + (size_t)(r0 + q16) * FEAT + (g << 6) + (q4 << 3));
  const half8 a0 = qp[0];   // e = q4*8 + [0..7]
  const half8 a1 = qp[4];   // e = 32 + q4*8 + [0..7]

  f32x4 S[16];
#pragma unroll
  for (int i = 0; i < 16; ++i) S[i] = (f32x4){0.f, 0.f, 0.f, 0.f};
#pragma unroll
  for (int t16 = 0; t16 < 16; ++t16) {
    const int n0 = nbase + (t16 << 4);
    const half8* kp = (const half8*)(kh + (size_t)(n0 + q16) * FEAT + (g << 6) + (q4 << 3));
    S[t16] = __builtin_amdgcn_mfma_f32_16x16x32_f16(a0, kp[0], S[t16], 0, 0, 0);
    S[t16] = __builtin_amdgcn_mfma_f32_16x16x32_f16(a1, kp[4], S[t16], 0, 0, 0);
  }

  // ---- logits = S*scale + logw ----
#pragma unroll
  for (int t16 = 0; t16 < 16; ++t16) {
    const int n = nbase + (t16 << 4) + q16;
#pragma unroll
    for (int j = 0; j < 4; ++j) {
      const int r = r0 + (q4 << 2) + j;
      const float lw = (float)logw[(size_t)(((r << 4) + g) << 10) + n];
      S[t16][j] = S[t16][j] * 0.125f + lw;
    }
  }

  // ---- row max (16-lane shuffle + cross-wave LDS) ----
  float m[4] = {-1e30f, -1e30f, -1e30f, -1e30f};
#pragma unroll
  for (int t16 = 0; t16 < 16; ++t16)
#pragma unroll
    for (int j = 0; j < 4; ++j) m[j] = fmaxf(m[j], S[t16][j]);
#pragma unroll
  for (int off = 8; off; off >>= 1)
#pragma unroll
    for (int j = 0; j < 4; ++j) m[j] = fmaxf(m[j], __shfl_xor(m[j], off));
  if (q16 == 0) {
#pragma unroll
    for (int j = 0; j < 4; ++j) redm[w][(q4 << 2) + j] = m[j];
  }
  __syncthreads();
#pragma unroll
  for (int j = 0; j < 4; ++j) {
    const int r = (q4 << 2) + j;
    m[j] = fmaxf(fmaxf(redm[0][r], redm[1][r]), fmaxf(redm[2][r], redm[3][r]));
  }

  // ---- exp, row-sum, P -> LDS f16 ----
  float ls[4] = {0.f, 0.f, 0.f, 0.f};
#pragma unroll
  for (int t16 = 0; t16 < 16; ++t16) {
    const int n = nbase + (t16 << 4) + q16;
#pragma unroll
    for (int j = 0; j < 4; ++j) {
      const float p = __expf(S[t16][j] - m[j]);
      ls[j] += p;
      P[(q4 << 2) + j][n] = (_Float16)p;
    }
  }
#pragma unroll
  for (int off = 8; off; off >>= 1)
#pragma unroll
    for (int j = 0; j < 4; ++j) ls[j] += __shfl_xor(ls[j], off);
  if (q16 == 0) {
#pragma unroll
    for (int j = 0; j < 4; ++j) redl[w][(q4 << 2) + j] = ls[j];
  }
  __syncthreads();   // P (same-wave) + redl visible

  // ---- PV: O[r][o] partial over this wave's 256 n; 4 o-tiles ----
  f32x4 O[4];
#pragma unroll
  for (int ot = 0; ot < 4; ++ot) O[ot] = (f32x4){0.f, 0.f, 0.f, 0.f};
#pragma unroll
  for (int ks = 0; ks < 8; ++ks) {
    const int nk = nbase + (ks << 5) + (q4 << 3);
    const half8 pa = *(const half8*)&P[q16][nk];
#pragma unroll
    for (int ot = 0; ot < 4; ++ot) {
      const half8 bfr = *(const half8*)(kct + (size_t)((g << 6) + (ot << 4) + q16) * N_DIM + nk);
      O[ot] = __builtin_amdgcn_mfma_f32_16x16x32_f16(pa, bfr, O[ot], 0, 0, 0);
    }
  }
#pragma unroll
  for (int ot = 0; ot < 4; ++ot)
#pragma unroll
    for (int j = 0; j < 4; ++j)
      Ored[w][(q4 << 2) + j][(ot << 4) + q16] = O[ot][j];
  __syncthreads();

  // ---- final cross-wave reduce + /l + bc ----
  const int r  = t >> 4;
  const int o0 = (t & 15) << 2;
  const float lsum = redl[0][r] + redl[1][r] + redl[2][r] + redl[3][r];
  const float inv  = 1.0f / lsum;
  float o[4];
#pragma unroll
  for (int c = 0; c < 4; ++c)
    o[c] = Ored[0][r][o0 + c] + Ored[1][r][o0 + c] + Ored[2][r][o0 + c] + Ored[3][r][o0 + c];
  const float4 bcv = *(const float4*)(bc + (g << 6) + o0);
  float4 res;
  res.x = o[0] * inv + bcv.x;
  res.y = o[1] * inv + bcv.y;
  res.z = o[2] * inv + bcv.z;
  res.w = o[3] * inv + bcv.w;
  *(float4*)(outp + (size_t)(r0 + r) * FEAT + (g << 6) + o0) = res;
}

// ---------------------------------------------------------------------------
extern "C" void kernel_launch(void* const* d_in, const int* in_sizes, int n_in,
                              void* d_out, int out_size, void* d_ws, size_t ws_size,
                              hipStream_t stream)
{
  const float* pe  = (const float*)d_in[0];
  const float* roi = (const float*)d_in[1];
  const float* Wq  = (const float*)d_in[2];
  const float* bq  = (const float*)d_in[3];
  const float* Wk  = (const float*)d_in[4];
  const float* bk  = (const float*)d_in[5];
  const float* Wp  = (const float*)d_in[6];
  const float* bp  = (const float*)d_in[7];
  const float* Wc  = (const float*)d_in[8];
  const float* bc  = (const float*)d_in[9];
  float* outp = (float*)d_out;

  char* ws = (char*)d_ws;
  _Float16* qh   = (_Float16*)(ws);                        // 2 MB
  _Float16* kh   = (_Float16*)(ws + ((size_t)2 << 20));    // 2 MB
  _Float16* kct  = (_Float16*)(ws + ((size_t)4 << 20));    // 2 MB [g][o][n]
  _Float16* logw = (_Float16*)(ws + ((size_t)6 << 20));    // 32 MB (total 38 MB)

  qk_gemm<<<dim3(16, 16), 256, 0, stream>>>(roi, Wq, bq, Wk, bk, qh, kh);
  pos_log<<<2048, 256, 0, stream>>>(pe, Wp, bp, logw);
  kc_gemm<<<dim3(16, 16), 256, 0, stream>>>(roi, Wc, kct);
  attn_mfma<<<dim3(64, 16), 256, 0, stream>>>(qh, kh, logw, kct, bc, outp);
}

// Round 5
// 229.118 us; speedup vs baseline: 3.0178x; 1.0291x over previous
//
#include <hip/hip_runtime.h>

#define R_DIM 1024
#define N_DIM 1024
#define FEAT  1024
#define EMB   64
#define GROUP 16
#define DG    64

typedef _Float16 half8  __attribute__((ext_vector_type(8)));
typedef _Float16 half4v __attribute__((ext_vector_type(4)));
typedef float    f32x4  __attribute__((ext_vector_type(4)));

// ---------------------------------------------------------------------------
// K1: qh = f16(roi @ Wq^T + bq), kh = f16(roi @ Wk^T + bk), both row-major
// [1024][1024] f16. fp32 accumulate in 64x64 tiles (BK=16), f16 on store only.
// ---------------------------------------------------------------------------
__global__ __launch_bounds__(256) void qk_gemm(
    const float* __restrict__ roi, const float* __restrict__ Wq,
    const float* __restrict__ bq,  const float* __restrict__ Wk,
    const float* __restrict__ bk,  _Float16* __restrict__ qh,
    _Float16* __restrict__ kh)
{
  __shared__ float aT[16][68];
  __shared__ float bqT[16][68];
  __shared__ float bkT[16][68];
  const int t  = threadIdx.x;
  const int r0 = blockIdx.x * 64, c0 = blockIdx.y * 64;
  const int lr = t >> 2, lk = (t & 3) << 2;
  const int ty = t >> 4, tx = t & 15;
  const float* ap  = roi + (r0 + lr) * FEAT + lk;
  const float* bqp = Wq  + (c0 + lr) * FEAT + lk;
  const float* bkp = Wk  + (c0 + lr) * FEAT + lk;
  float4 av  = *(const float4*)ap;
  float4 bqv = *(const float4*)bqp;
  float4 bkv = *(const float4*)bkp;
  float accq[4][4] = {}, acck[4][4] = {};
  for (int k0 = 0; k0 < FEAT; k0 += 16) {
    aT[lk+0][lr]=av.x;   aT[lk+1][lr]=av.y;   aT[lk+2][lr]=av.z;   aT[lk+3][lr]=av.w;
    bqT[lk+0][lr]=bqv.x; bqT[lk+1][lr]=bqv.y; bqT[lk+2][lr]=bqv.z; bqT[lk+3][lr]=bqv.w;
    bkT[lk+0][lr]=bkv.x; bkT[lk+1][lr]=bkv.y; bkT[lk+2][lr]=bkv.z; bkT[lk+3][lr]=bkv.w;
    __syncthreads();
    const bool more = (k0 + 16) < FEAT;
    float4 av_n, bqv_n, bkv_n;
    if (more) {
      av_n  = *(const float4*)(ap  + k0 + 16);
      bqv_n = *(const float4*)(bqp + k0 + 16);
      bkv_n = *(const float4*)(bkp + k0 + 16);
    }
#pragma unroll
    for (int kk = 0; kk < 16; ++kk) {
      const float4 a4 = *(const float4*)&aT[kk][ty << 2];
      const float4 q4 = *(const float4*)&bqT[kk][tx << 2];
      const float4 k4 = *(const float4*)&bkT[kk][tx << 2];
      const float ar[4] = {a4.x, a4.y, a4.z, a4.w};
      const float qr[4] = {q4.x, q4.y, q4.z, q4.w};
      const float kr[4] = {k4.x, k4.y, k4.z, k4.w};
#pragma unroll
      for (int i = 0; i < 4; ++i)
#pragma unroll
        for (int j = 0; j < 4; ++j) {
          accq[i][j] += ar[i] * qr[j];
          acck[i][j] += ar[i] * kr[j];
        }
    }
    __syncthreads();
    if (more) { av = av_n; bqv = bqv_n; bkv = bkv_n; }
  }
  const float4 bq4 = *(const float4*)(bq + c0 + (tx << 2));
  const float4 bk4 = *(const float4*)(bk + c0 + (tx << 2));
  const float bqr[4] = {bq4.x, bq4.y, bq4.z, bq4.w};
  const float bkr[4] = {bk4.x, bk4.y, bk4.z, bk4.w};
#pragma unroll
  for (int i = 0; i < 4; ++i) {
    half4v oq, ok;
#pragma unroll
    for (int j = 0; j < 4; ++j) {
      oq[j] = (_Float16)(accq[i][j] + bqr[j]);
      ok[j] = (_Float16)(acck[i][j] + bkr[j]);
    }
    const int row = r0 + (ty << 2) + i;
    *(half4v*)(qh + (size_t)row * FEAT + c0 + (tx << 2)) = oq;
    *(half4v*)(kh + (size_t)row * FEAT + c0 + (tx << 2)) = ok;
  }
}

// ---------------------------------------------------------------------------
// K2: logw[r,g,n] = log(max(relu(pos_emb[r,n,:].Wp[g,:] + bp[g]), 1e-6)), f16
// R4 rework: coalesced LDS-staged pe tile (R0 version had lanes 256B apart ->
// 64 transactions/load). 128 rows/block; thread owns one row; Wp/bp read via
// wave-uniform global addresses (scalarized to s_load, 4KB hot in sL1).
// ---------------------------------------------------------------------------
__global__ __launch_bounds__(128) void pos_log(
    const float* __restrict__ pe, const float* __restrict__ Wp,
    const float* __restrict__ bp, _Float16* __restrict__ logw)
{
  __shared__ float tile[128 * 68];          // 34.8 KB, row stride 68 (bank-balanced)
  const int t    = threadIdx.x;
  const int base = blockIdx.x << 7;         // 8192 blocks * 128 rows
  const int r    = base >> 10;
  const int n0   = base & 1023;
  const float* src = pe + ((size_t)base << 6);
#pragma unroll
  for (int i = 0; i < 16; ++i) {
    const int flat = (i << 7) + t;          // float4 index into 128x16 tile
    const int rl = flat >> 4, e4 = flat & 15;
    const float4 v = *(const float4*)(src + ((size_t)flat << 2));   // coalesced
    *(float4*)&tile[rl * 68 + (e4 << 2)] = v;
  }
  __syncthreads();
  float acc[16];
#pragma unroll
  for (int g = 0; g < 16; ++g) acc[g] = bp[g];
#pragma unroll
  for (int e4 = 0; e4 < 16; ++e4) {
    const float4 x = *(const float4*)&tile[t * 68 + (e4 << 2)];
#pragma unroll
    for (int g = 0; g < 16; ++g) {
      const float4 w = *(const float4*)(Wp + (g << 6) + (e4 << 2)); // uniform -> s_load
      acc[g] += x.x*w.x + x.y*w.y + x.z*w.z + x.w*w.w;
    }
  }
  const int n = n0 + t;
#pragma unroll
  for (int g = 0; g < 16; ++g) {
    const float v = fmaxf(acc[g], 1e-6f);   // relu then clip == max(x,1e-6)
    logw[((size_t)((r << 4) + g) << 10) + n] = (_Float16)__logf(v);
  }
}

// ---------------------------------------------------------------------------
// K3: kct[g][o][n] = f16( sum_f Wc[g][o][f] * roi[n][f] )  (KC transposed so
// PV B-fragments are contiguous 16B loads). A = Wc[g] (rows o), B = roi (rows n).
// ---------------------------------------------------------------------------
__global__ __launch_bounds__(256) void kc_gemm(
    const float* __restrict__ roi, const float* __restrict__ Wc,
    _Float16* __restrict__ kct)
{
  __shared__ float aT[16][68];
  __shared__ float bT[16][68];
  const int t  = threadIdx.x;
  const int n0 = blockIdx.x * 64;
  const int g  = blockIdx.y;
  const int lr = t >> 2, lk = (t & 3) << 2;
  const int ty = t >> 4, tx = t & 15;
  const float* ap  = Wc  + (size_t)(g * DG + lr) * FEAT + lk;  // o-rows
  const float* bp_ = roi + (size_t)(n0 + lr) * FEAT + lk;      // n-rows
  float4 av = *(const float4*)ap;
  float4 bv = *(const float4*)bp_;
  float acc[4][4] = {};
  for (int k0 = 0; k0 < FEAT; k0 += 16) {
    aT[lk+0][lr]=av.x; aT[lk+1][lr]=av.y; aT[lk+2][lr]=av.z; aT[lk+3][lr]=av.w;
    bT[lk+0][lr]=bv.x; bT[lk+1][lr]=bv.y; bT[lk+2][lr]=bv.z; bT[lk+3][lr]=bv.w;
    __syncthreads();
    const bool more = (k0 + 16) < FEAT;
    float4 av_n, bv_n;
    if (more) {
      av_n = *(const float4*)(ap  + k0 + 16);
      bv_n = *(const float4*)(bp_ + k0 + 16);
    }
#pragma unroll
    for (int kk = 0; kk < 16; ++kk) {
      const float4 a4 = *(const float4*)&aT[kk][ty << 2];
      const float4 b4 = *(const float4*)&bT[kk][tx << 2];
      const float ar[4] = {a4.x, a4.y, a4.z, a4.w};
      const float br[4] = {b4.x, b4.y, b4.z, b4.w};
#pragma unroll
      for (int i = 0; i < 4; ++i)
#pragma unroll
        for (int j = 0; j < 4; ++j) acc[i][j] += ar[i] * br[j];
    }
    __syncthreads();
    if (more) { av = av_n; bv = bv_n; }
  }
  // acc[i][j]: o = ty*4+i, n = n0+tx*4+j  ->  kct[(g*64+o)*1024 + n]
#pragma unroll
  for (int i = 0; i < 4; ++i) {
    half4v o4;
#pragma unroll
    for (int j = 0; j < 4; ++j) o4[j] = (_Float16)acc[i][j];
    *(half4v*)(kct + (size_t)((g << 6) + (ty << 2) + i) * N_DIM + n0 + (tx << 2)) = o4;
  }
}

// ---------------------------------------------------------------------------
// K4: MFMA attention. Block = 16 q-rows x one g, 4 waves; wave w owns n-strip
// [w*256, w*256+256). QK^T and PV via v_mfma_f32_16x16x32_f16 (fp32 accum).
// Fragment maps (CDNA): A row=lane&15, k=(lane>>4)*8+j ; B col=lane&15, same k;
// C/D col=lane&15, row=(lane>>4)*4+reg (m89-verified).
// P staged in LDS f16, rows padded to 1032 (2064B: 16B-aligned, bank-uniform).
// ---------------------------------------------------------------------------
#define PLD 1032
__global__ __launch_bounds__(256) void attn_mfma(
    const _Float16* __restrict__ qh, const _Float16* __restrict__ kh,
    const _Float16* __restrict__ logw, const _Float16* __restrict__ kct,
    const float* __restrict__ bc, float* __restrict__ outp)
{
  __shared__ __align__(16) _Float16 P[16][PLD];   // 33,024 B
  __shared__ float Ored[4][16][68];               // 17,408 B
  __shared__ float redm[4][16];
  __shared__ float redl[4][16];

  const int t   = threadIdx.x;
  const int w   = t >> 6;
  const int l   = t & 63;
  const int q16 = l & 15;          // A-row / B-col / D-col
  const int q4  = l >> 4;          // k-quarter / D-row-quarter
  const int g   = blockIdx.y;
  const int r0  = blockIdx.x << 4;
  const int nbase = w << 8;

  // ---- QK^T: S[16 tiles], each 16x16 over this wave's 256 n ----
  const half8* qp = (const half8*)(qh + (size_t)(r0 + q16) * FEAT + (g << 6) + (q4 << 3));
  const half8 a0 = qp[0];   // e = q4*8 + [0..7]
  const half8 a1 = qp[4];   // e = 32 + q4*8 + [0..7]

  f32x4 S[16];
#pragma unroll
  for (int i = 0; i < 16; ++i) S[i] = (f32x4){0.f, 0.f, 0.f, 0.f};
#pragma unroll
  for (int t16 = 0; t16 < 16; ++t16) {
    const int n0 = nbase + (t16 << 4);
    const half8* kp = (const half8*)(kh + (size_t)(n0 + q16) * FEAT + (g << 6) + (q4 << 3));
    S[t16] = __builtin_amdgcn_mfma_f32_16x16x32_f16(a0, kp[0], S[t16], 0, 0, 0);
    S[t16] = __builtin_amdgcn_mfma_f32_16x16x32_f16(a1, kp[4], S[t16], 0, 0, 0);
  }

  // ---- logits = S*scale + logw ----
#pragma unroll
  for (int t16 = 0; t16 < 16; ++t16) {
    const int n = nbase + (t16 << 4) + q16;
#pragma unroll
    for (int j = 0; j < 4; ++j) {
      const int r = r0 + (q4 << 2) + j;
      const float lw = (float)logw[(size_t)(((r << 4) + g) << 10) + n];
      S[t16][j] = S[t16][j] * 0.125f + lw;
    }
  }

  // ---- row max (16-lane shuffle + cross-wave LDS) ----
  float m[4] = {-1e30f, -1e30f, -1e30f, -1e30f};
#pragma unroll
  for (int t16 = 0; t16 < 16; ++t16)
#pragma unroll
    for (int j = 0; j < 4; ++j) m[j] = fmaxf(m[j], S[t16][j]);
#pragma unroll
  for (int off = 8; off; off >>= 1)
#pragma unroll
    for (int j = 0; j < 4; ++j) m[j] = fmaxf(m[j], __shfl_xor(m[j], off));
  if (q16 == 0) {
#pragma unroll
    for (int j = 0; j < 4; ++j) redm[w][(q4 << 2) + j] = m[j];
  }
  __syncthreads();
#pragma unroll
  for (int j = 0; j < 4; ++j) {
    const int r = (q4 << 2) + j;
    m[j] = fmaxf(fmaxf(redm[0][r], redm[1][r]), fmaxf(redm[2][r], redm[3][r]));
  }

  // ---- exp, row-sum, P -> LDS f16 ----
  float ls[4] = {0.f, 0.f, 0.f, 0.f};
#pragma unroll
  for (int t16 = 0; t16 < 16; ++t16) {
    const int n = nbase + (t16 << 4) + q16;
#pragma unroll
    for (int j = 0; j < 4; ++j) {
      const float p = __expf(S[t16][j] - m[j]);
      ls[j] += p;
      P[(q4 << 2) + j][n] = (_Float16)p;
    }
  }
#pragma unroll
  for (int off = 8; off; off >>= 1)
#pragma unroll
    for (int j = 0; j < 4; ++j) ls[j] += __shfl_xor(ls[j], off);
  if (q16 == 0) {
#pragma unroll
    for (int j = 0; j < 4; ++j) redl[w][(q4 << 2) + j] = ls[j];
  }
  __syncthreads();   // P (same-wave) + redl visible

  // ---- PV: O[r][o] partial over this wave's 256 n; 4 o-tiles ----
  f32x4 O[4];
#pragma unroll
  for (int ot = 0; ot < 4; ++ot) O[ot] = (f32x4){0.f, 0.f, 0.f, 0.f};
#pragma unroll
  for (int ks = 0; ks < 8; ++ks) {
    const int nk = nbase + (ks << 5) + (q4 << 3);
    const half8 pa = *(const half8*)&P[q16][nk];
#pragma unroll
    for (int ot = 0; ot < 4; ++ot) {
      const half8 bfr = *(const half8*)(kct + (size_t)((g << 6) + (ot << 4) + q16) * N_DIM + nk);
      O[ot] = __builtin_amdgcn_mfma_f32_16x16x32_f16(pa, bfr, O[ot], 0, 0, 0);
    }
  }
#pragma unroll
  for (int ot = 0; ot < 4; ++ot)
#pragma unroll
    for (int j = 0; j < 4; ++j)
      Ored[w][(q4 << 2) + j][(ot << 4) + q16] = O[ot][j];
  __syncthreads();

  // ---- final cross-wave reduce + /l + bc ----
  const int r  = t >> 4;
  const int o0 = (t & 15) << 2;
  const float lsum = redl[0][r] + redl[1][r] + redl[2][r] + redl[3][r];
  const float inv  = 1.0f / lsum;
  float o[4];
#pragma unroll
  for (int c = 0; c < 4; ++c)
    o[c] = Ored[0][r][o0 + c] + Ored[1][r][o0 + c] + Ored[2][r][o0 + c] + Ored[3][r][o0 + c];
  const float4 bcv = *(const float4*)(bc + (g << 6) + o0);
  float4 res;
  res.x = o[0] * inv + bcv.x;
  res.y = o[1] * inv + bcv.y;
  res.z = o[2] * inv + bcv.z;
  res.w = o[3] * inv + bcv.w;
  *(float4*)(outp + (size_t)(r0 + r) * FEAT + (g << 6) + o0) = res;
}

// ---------------------------------------------------------------------------
extern "C" void kernel_launch(void* const* d_in, const int* in_sizes, int n_in,
                              void* d_out, int out_size, void* d_ws, size_t ws_size,
                              hipStream_t stream)
{
  const float* pe  = (const float*)d_in[0];
  const float* roi = (const float*)d_in[1];
  const float* Wq  = (const float*)d_in[2];
  const float* bq  = (const float*)d_in[3];
  const float* Wk  = (const float*)d_in[4];
  const float* bk  = (const float*)d_in[5];
  const float* Wp  = (const float*)d_in[6];
  const float* bp  = (const float*)d_in[7];
  const float* Wc  = (const float*)d_in[8];
  const float* bc  = (const float*)d_in[9];
  float* outp = (float*)d_out;

  char* ws = (char*)d_ws;
  _Float16* qh   = (_Float16*)(ws);                        // 2 MB
  _Float16* kh   = (_Float16*)(ws + ((size_t)2 << 20));    // 2 MB
  _Float16* kct  = (_Float16*)(ws + ((size_t)4 << 20));    // 2 MB [g][o][n]
  _Float16* logw = (_Float16*)(ws + ((size_t)6 << 20));    // 32 MB (total 38 MB)

  qk_gemm<<<dim3(16, 16), 256, 0, stream>>>(roi, Wq, bq, Wk, bk, qh, kh);
  pos_log<<<8192, 128, 0, stream>>>(pe, Wp, bp, logw);
  kc_gemm<<<dim3(16, 16), 256, 0, stream>>>(roi, Wc, kct);
  attn_mfma<<<dim3(64, 16), 256, 0, stream>>>(qh, kh, logw, kct, bc, outp);
}